// Round 1
// baseline (525.706 us; speedup 1.0000x reference)
//
#include <hip/hip_runtime.h>
#include <hip/hip_bf16.h>
#include <cstdint>
#include <cstddef>

// ---------------------------------------------------------------------------
// AutoEncoder: x[8192,1024] -> enc(1024->2048->2048->64, relu/relu/sigmoid)
//             -> dec(64->2048->2048->1024, relu/relu/none)
// Strategy: cast/transpose weights + x to bf16 once per launch, then 6
// m97-style MFMA GEMMs (128x128 tile, BK=32, global_load_lds width=16,
// v_mfma_f32_16x16x32_bf16, fp32 accumulate, fused bias+activation epilogue).
// ---------------------------------------------------------------------------

typedef __bf16 bf16_t;
typedef bf16_t bf16x8 __attribute__((ext_vector_type(8)));
typedef bf16_t bf16x4 __attribute__((ext_vector_type(4)));
typedef float  floatx4 __attribute__((ext_vector_type(4)));

__device__ __forceinline__ void async_cp16(const bf16_t* gp, bf16_t* lp) {
    // direct global->LDS DMA, 16B per lane; LDS dest is wave-uniform base + lane*16
    __builtin_amdgcn_global_load_lds(
        (const __attribute__((address_space(1))) void*)gp,
        (__attribute__((address_space(3))) void*)lp, 16, 0, 0);
}

// fp32 -> bf16 elementwise cast (x), 4 elts/thread, exact-size grid
__global__ void cast_to_bf16(const float* __restrict__ in, bf16_t* __restrict__ out) {
    const int i = (blockIdx.x * blockDim.x + threadIdx.x) * 4;
    const float4 v = *(const float4*)(in + i);
    bf16x4 o;
    o[0] = (bf16_t)v.x; o[1] = (bf16_t)v.y; o[2] = (bf16_t)v.z; o[3] = (bf16_t)v.w;
    *(bf16x4*)(out + i) = o;
}

// in[K,N] fp32 -> out[N,K] bf16, 32x32 LDS tile transpose (K,N multiples of 32)
__global__ void transpose_cast(const float* __restrict__ in, bf16_t* __restrict__ out,
                               int K, int N) {
    __shared__ float tile[32][33];
    const int n0 = blockIdx.x * 32, k0 = blockIdx.y * 32;
    const int tx = threadIdx.x, ty = threadIdx.y;
#pragma unroll
    for (int i = 0; i < 32; i += 8)
        tile[ty + i][tx] = in[(size_t)(k0 + ty + i) * N + n0 + tx];
    __syncthreads();
#pragma unroll
    for (int i = 0; i < 32; i += 8)
        out[(size_t)(n0 + ty + i) * K + k0 + tx] = (bf16_t)tile[tx][ty + i];
}

// C[M,N] = act(A[M,K] @ Bt[N,K]^T + bias), OMODE bit0: bf16 out, bit1: f32 out
// ACT: 0 none, 1 relu, 2 sigmoid
template<int BM, int BN, int WM, int WN, int ACT, int OMODE>
__global__ __launch_bounds__(256)
void gemm_bt(const bf16_t* __restrict__ A, const bf16_t* __restrict__ Bt,
             const float* __restrict__ bias,
             bf16_t* __restrict__ Cb, float* __restrict__ Cf,
             int M, int N, int K) {
    constexpr int BK = 32;
    constexpr int MI = WM / 16, NI = WN / 16;
    constexpr int WCOLS = BN / WN;
    static_assert((BM / WM) * (BN / WN) == 4, "4 waves");
    constexpr int A_CPW = (BM * BK) / (8 * 64 * 4);  // 16B chunks per wave per k-step
    constexpr int B_CPW = (BN * BK) / (8 * 64 * 4);
    static_assert(A_CPW >= 1 && B_CPW >= 1, "tile too small");

    __shared__ bf16_t As[BM * BK];   // [BM][32] row-major (K-contiguous)
    __shared__ bf16_t Bs[BN * BK];   // [BN][32] row-major (K-contiguous)

    const int tid  = threadIdx.x;
    const int wave = tid >> 6;
    const int lane = tid & 63;
    const int m0 = blockIdx.y * BM;
    const int n0 = blockIdx.x * BN;
    const int wm0 = (wave / WCOLS) * WM;
    const int wn0 = (wave % WCOLS) * WN;

    floatx4 acc[MI][NI];
#pragma unroll
    for (int i = 0; i < MI; ++i)
#pragma unroll
        for (int j = 0; j < NI; ++j)
            acc[i][j] = floatx4{0.f, 0.f, 0.f, 0.f};

    const int r15 = lane & 15;
    const int kg  = (lane >> 4) * 8;   // K-group for MFMA operand

    for (int kt = 0; kt < K; kt += BK) {
        __syncthreads();  // all waves done reading previous tile
#pragma unroll
        for (int i = 0; i < A_CPW; ++i) {
            const int cbase = (wave * A_CPW + i) * 64;     // chunk base (8-elt chunks)
            const int chunk = cbase + lane;
            const int row = chunk >> 2;                     // 4 chunks per 32-elt row
            const int c8  = (chunk & 3) * 8;
            async_cp16(A + (size_t)(m0 + row) * K + kt + c8, As + (size_t)cbase * 8);
        }
#pragma unroll
        for (int i = 0; i < B_CPW; ++i) {
            const int cbase = (wave * B_CPW + i) * 64;
            const int chunk = cbase + lane;
            const int row = chunk >> 2;
            const int c8  = (chunk & 3) * 8;
            async_cp16(Bt + (size_t)(n0 + row) * K + kt + c8, Bs + (size_t)cbase * 8);
        }
        __syncthreads();  // compiler drains vmcnt before barrier -> staging visible

        bf16x8 af[MI], bfr[NI];
#pragma unroll
        for (int i = 0; i < MI; ++i)
            af[i] = *(const bf16x8*)(As + (wm0 + i * 16 + r15) * BK + kg);
#pragma unroll
        for (int j = 0; j < NI; ++j)
            bfr[j] = *(const bf16x8*)(Bs + (wn0 + j * 16 + r15) * BK + kg);
#pragma unroll
        for (int i = 0; i < MI; ++i)
#pragma unroll
            for (int j = 0; j < NI; ++j)
                acc[i][j] = __builtin_amdgcn_mfma_f32_16x16x32_bf16(
                    af[i], bfr[j], acc[i][j], 0, 0, 0);
    }

    // epilogue: C/D layout col=lane&15, row=(lane>>4)*4+reg (m89/m91 verified)
    const int row_l = (lane >> 4) * 4;
#pragma unroll
    for (int j = 0; j < NI; ++j) {
        const int n = n0 + wn0 + j * 16 + r15;
        const float bv = bias[n];
#pragma unroll
        for (int i = 0; i < MI; ++i) {
            const int m = m0 + wm0 + i * 16 + row_l;
#pragma unroll
            for (int r = 0; r < 4; ++r) {
                float f = acc[i][j][r] + bv;
                if (ACT == 1) f = fmaxf(f, 0.f);
                if (ACT == 2) f = 1.f / (1.f + __expf(-f));
                const size_t idx = (size_t)(m + r) * N + n;
                if (OMODE & 1) Cb[idx] = (bf16_t)f;
                if (OMODE & 2) Cf[idx] = f;
            }
        }
    }
}

extern "C" void kernel_launch(void* const* d_in, const int* in_sizes, int n_in,
                              void* d_out, int out_size, void* d_ws, size_t ws_size,
                              hipStream_t stream) {
    const float* x   = (const float*)d_in[0];
    const float* We1 = (const float*)d_in[1];
    const float* be1 = (const float*)d_in[2];
    const float* We2 = (const float*)d_in[3];
    const float* be2 = (const float*)d_in[4];
    const float* We3 = (const float*)d_in[5];
    const float* be3 = (const float*)d_in[6];
    const float* Wd1 = (const float*)d_in[7];
    const float* bd1 = (const float*)d_in[8];
    const float* Wd2 = (const float*)d_in[9];
    const float* bd2 = (const float*)d_in[10];
    const float* Wd3 = (const float*)d_in[11];
    const float* bd3 = (const float*)d_in[12];

    char* ws = (char*)d_ws;
    size_t off = 0;
    bf16_t* xb  = (bf16_t*)(ws + off); off += (size_t)8192 * 1024 * 2;  // x bf16
    bf16_t* w1t = (bf16_t*)(ws + off); off += (size_t)2048 * 1024 * 2;  // We1^T [2048,1024]
    bf16_t* w2t = (bf16_t*)(ws + off); off += (size_t)2048 * 2048 * 2;  // We2^T
    bf16_t* w3t = (bf16_t*)(ws + off); off += (size_t)64   * 2048 * 2;  // We3^T [64,2048]
    bf16_t* w4t = (bf16_t*)(ws + off); off += (size_t)2048 * 64   * 2;  // Wd1^T [2048,64]
    bf16_t* w5t = (bf16_t*)(ws + off); off += (size_t)2048 * 2048 * 2;  // Wd2^T
    bf16_t* w6t = (bf16_t*)(ws + off); off += (size_t)1024 * 2048 * 2;  // Wd3^T [1024,2048]
    bf16_t* ha  = (bf16_t*)(ws + off); off += (size_t)8192 * 2048 * 2;  // hidden ping
    bf16_t* hb  = (bf16_t*)(ws + off); off += (size_t)8192 * 2048 * 2;  // hidden pong
    bf16_t* cb  = (bf16_t*)(ws + off); off += (size_t)8192 * 64   * 2;  // control bf16
    // total ~110.6 MB of ws

    float* out0 = (float*)d_out;                    // control_vec [8192,64]
    float* out1 = out0 + (size_t)8192 * 64;         // state_vec   [8192,1024]

    // --- precision conversion / weight transpose (per-launch, ~75MB traffic) ---
    cast_to_bf16<<<dim3(8192), dim3(256), 0, stream>>>(x, xb);
    const dim3 tb(32, 8);
    transpose_cast<<<dim3(2048 / 32, 1024 / 32), tb, 0, stream>>>(We1, w1t, 1024, 2048);
    transpose_cast<<<dim3(2048 / 32, 2048 / 32), tb, 0, stream>>>(We2, w2t, 2048, 2048);
    transpose_cast<<<dim3(64 / 32,   2048 / 32), tb, 0, stream>>>(We3, w3t, 2048, 64);
    transpose_cast<<<dim3(2048 / 32, 64 / 32),   tb, 0, stream>>>(Wd1, w4t, 64, 2048);
    transpose_cast<<<dim3(2048 / 32, 2048 / 32), tb, 0, stream>>>(Wd2, w5t, 2048, 2048);
    transpose_cast<<<dim3(1024 / 32, 2048 / 32), tb, 0, stream>>>(Wd3, w6t, 2048, 1024);

    // --- 6-layer GEMM chain (grid = (N/BN, M/BM)) ---
    // e1: relu(x @ We1 + be1)            M=8192 K=1024 N=2048
    gemm_bt<128, 128, 64, 64, 1, 1><<<dim3(16, 64), 256, 0, stream>>>(
        xb, w1t, be1, ha, nullptr, 8192, 2048, 1024);
    // e2: relu(h @ We2 + be2)            K=2048 N=2048
    gemm_bt<128, 128, 64, 64, 1, 1><<<dim3(16, 64), 256, 0, stream>>>(
        ha, w2t, be2, hb, nullptr, 8192, 2048, 2048);
    // e3: sigmoid(h @ We3 + be3) -> cb (bf16) + out0 (f32)   K=2048 N=64
    gemm_bt<128, 64, 32, 64, 2, 3><<<dim3(1, 64), 256, 0, stream>>>(
        hb, w3t, be3, cb, out0, 8192, 64, 2048);
    // d1: relu(c @ Wd1 + bd1)            K=64 N=2048
    gemm_bt<128, 128, 64, 64, 1, 1><<<dim3(16, 64), 256, 0, stream>>>(
        cb, w4t, bd1, ha, nullptr, 8192, 2048, 64);
    // d2: relu(h @ Wd2 + bd2)            K=2048 N=2048
    gemm_bt<128, 128, 64, 64, 1, 1><<<dim3(16, 64), 256, 0, stream>>>(
        ha, w5t, bd2, hb, nullptr, 8192, 2048, 2048);
    // d3: h @ Wd3 + bd3 -> out1 (f32)    K=2048 N=1024
    gemm_bt<128, 128, 64, 64, 0, 2><<<dim3(8, 64), 256, 0, stream>>>(
        hb, w6t, bd3, nullptr, out1, 8192, 1024, 2048);
}

// Round 2
// 502.559 us; speedup vs baseline: 1.0461x; 1.0461x over previous
//
#include <hip/hip_runtime.h>
#include <hip/hip_bf16.h>
#include <cstdint>
#include <cstddef>

// ---------------------------------------------------------------------------
// AutoEncoder: x[8192,1024] -> enc(1024->2048->2048->64, relu/relu/sigmoid)
//             -> dec(64->2048->2048->1024, relu/relu/none)
// R2 changes vs R1:
//  - LDS K-chunk swizzle (slot = (c + (row>>1)) & 3) kills the 8-way bank
//    conflict on ds_read_b128 fragment loads (8.39M conflicts/dispatch in R1).
//  - All 7 conversion kernels merged into one `prep` launch.
//  - e3 (N=64, was 64-block grid) now split-K x4 into fp32 partials (reusing
//    dead `ha` buffer) + tiny reduce kernel with bias+sigmoid.
// ---------------------------------------------------------------------------

typedef __bf16 bf16_t;
typedef bf16_t bf16x8 __attribute__((ext_vector_type(8)));
typedef bf16_t bf16x4 __attribute__((ext_vector_type(4)));
typedef float  floatx4 __attribute__((ext_vector_type(4)));

__device__ __forceinline__ void async_cp16(const bf16_t* gp, bf16_t* lp) {
    // global->LDS DMA, 16B/lane; LDS dest = wave-uniform base + lane*16
    __builtin_amdgcn_global_load_lds(
        (const __attribute__((address_space(1))) void*)gp,
        (__attribute__((address_space(3))) void*)lp, 16, 0, 0);
}

// ---------------------------------------------------------------------------
// Merged prep: x fp32->bf16 cast + 6 weight transpose+casts in one launch.
// Block 0..8191: x cast. Blocks 8192..20735: 32x32 transpose tiles.
// ---------------------------------------------------------------------------
struct PrepArgs {
    const float* x; bf16_t* xb;
    const float* w[6]; bf16_t* t[6];
};

__device__ __forceinline__ void trans_tile(const float* __restrict__ in,
                                           bf16_t* __restrict__ out,
                                           int K, int N, int bx, int by,
                                           int tx, int ty,
                                           float (*tile)[33]) {
    const int n0 = bx * 32, k0 = by * 32;
#pragma unroll
    for (int i = 0; i < 32; i += 8)
        tile[ty + i][tx] = in[(size_t)(k0 + ty + i) * N + n0 + tx];
    __syncthreads();
#pragma unroll
    for (int i = 0; i < 32; i += 8)
        out[(size_t)(n0 + ty + i) * K + k0 + tx] = (bf16_t)tile[tx][ty + i];
}

__global__ __launch_bounds__(256) void prep(PrepArgs a) {
    __shared__ float tile[32][33];
    const int tx = threadIdx.x, ty = threadIdx.y;
    const int b = blockIdx.x;
    if (b < 8192) {                      // x cast: 8192*1024 elts, 4/thread
        const int i = (b * 256 + ty * 32 + tx) * 4;
        const float4 v = *(const float4*)(a.x + i);
        bf16x4 o;
        o[0] = (bf16_t)v.x; o[1] = (bf16_t)v.y;
        o[2] = (bf16_t)v.z; o[3] = (bf16_t)v.w;
        *(bf16x4*)(a.xb + i) = o;
        return;
    }
    int lb = b - 8192;
    // weights: (K,N) fp32 -> (N,K) bf16. tile counts: (N/32)*(K/32)
    if (lb < 2048)      { trans_tile(a.w[0], a.t[0], 1024, 2048, lb % 64, lb / 64, tx, ty, tile); return; }
    lb -= 2048;
    if (lb < 4096)      { trans_tile(a.w[1], a.t[1], 2048, 2048, lb % 64, lb / 64, tx, ty, tile); return; }
    lb -= 4096;
    if (lb < 128)       { trans_tile(a.w[2], a.t[2], 2048, 64,   lb % 2,  lb / 2,  tx, ty, tile); return; }
    lb -= 128;
    if (lb < 128)       { trans_tile(a.w[3], a.t[3], 64,   2048, lb % 64, lb / 64, tx, ty, tile); return; }
    lb -= 128;
    if (lb < 4096)      { trans_tile(a.w[4], a.t[4], 2048, 2048, lb % 64, lb / 64, tx, ty, tile); return; }
    lb -= 4096;
    trans_tile(a.w[5], a.t[5], 2048, 1024, lb % 32, lb / 32, tx, ty, tile);
}

// ---------------------------------------------------------------------------
// C[M,N] = act(A[M,K'] @ Bt[N,K']^T + bias) over K-segment [kz0, kz0+K)
// where kz0 = blockIdx.z * K, ld = row stride of A and Bt (= full K').
// OMODE bit0: bf16 out, bit1: f32 out, bit2: f32 split-K partial (no bias/act)
// ACT: 0 none, 1 relu, 2 sigmoid
// LDS layout swizzle: 16B chunk at (row, slot) holds global K-chunk
// c = (slot - (row>>1)) & 3  ->  reader slot for K-group g is (g + (row>>1)) & 3.
// This spreads ds_read_b128 across all 8 16B-bank-groups (2-way = free, m136).
// ---------------------------------------------------------------------------
template<int BM, int BN, int WM, int WN, int ACT, int OMODE>
__global__ __launch_bounds__(256)
void gemm_bt(const bf16_t* __restrict__ A, const bf16_t* __restrict__ Bt,
             const float* __restrict__ bias,
             bf16_t* __restrict__ Cb, float* __restrict__ Cf,
             int M, int N, int K, int ld) {
    constexpr int BK = 32;
    constexpr int MI = WM / 16, NI = WN / 16;
    constexpr int WCOLS = BN / WN;
    static_assert((BM / WM) * (BN / WN) == 4, "4 waves");
    constexpr int A_CPW = (BM * BK) / (8 * 64 * 4);
    constexpr int B_CPW = (BN * BK) / (8 * 64 * 4);
    static_assert(A_CPW >= 1 && B_CPW >= 1, "tile too small");

    __shared__ bf16_t As[BM * BK];
    __shared__ bf16_t Bs[BN * BK];

    const int tid  = threadIdx.x;
    const int wave = tid >> 6;
    const int lane = tid & 63;
    const int m0 = blockIdx.y * BM;
    const int n0 = blockIdx.x * BN;
    const int kz0 = blockIdx.z * K;
    const int wm0 = (wave / WCOLS) * WM;
    const int wn0 = (wave % WCOLS) * WN;
    const int r15 = lane & 15;
    const int kgc = lane >> 4;          // K-group 0..3 (8 elts each)

    floatx4 acc[MI][NI];
#pragma unroll
    for (int i = 0; i < MI; ++i)
#pragma unroll
        for (int j = 0; j < NI; ++j)
            acc[i][j] = floatx4{0.f, 0.f, 0.f, 0.f};

    // staging source offsets (constant across k-loop): chunk -> (row, c8)
    int a_row[A_CPW], a_c8[A_CPW], a_dst[A_CPW];
#pragma unroll
    for (int i = 0; i < A_CPW; ++i) {
        const int cbase = (wave * A_CPW + i) * 64;
        const int chunk = cbase + lane;
        a_row[i] = chunk >> 2;
        a_c8[i]  = (((chunk & 3) - (a_row[i] >> 1)) & 3) * 8;
        a_dst[i] = cbase * 8;
    }
    int b_row[B_CPW], b_c8[B_CPW], b_dst[B_CPW];
#pragma unroll
    for (int i = 0; i < B_CPW; ++i) {
        const int cbase = (wave * B_CPW + i) * 64;
        const int chunk = cbase + lane;
        b_row[i] = chunk >> 2;
        b_c8[i]  = (((chunk & 3) - (b_row[i] >> 1)) & 3) * 8;
        b_dst[i] = cbase * 8;
    }
    // fragment LDS offsets (constant across k-loop)
    int a_off[MI], b_off[NI];
#pragma unroll
    for (int i = 0; i < MI; ++i) {
        const int r = wm0 + i * 16 + r15;
        a_off[i] = r * BK + (((kgc + (r >> 1)) & 3) << 3);
    }
#pragma unroll
    for (int j = 0; j < NI; ++j) {
        const int r = wn0 + j * 16 + r15;
        b_off[j] = r * BK + (((kgc + (r >> 1)) & 3) << 3);
    }

    for (int kt = 0; kt < K; kt += BK) {
        __syncthreads();
#pragma unroll
        for (int i = 0; i < A_CPW; ++i)
            async_cp16(A + (size_t)(m0 + a_row[i]) * ld + kz0 + kt + a_c8[i],
                       As + a_dst[i]);
#pragma unroll
        for (int i = 0; i < B_CPW; ++i)
            async_cp16(Bt + (size_t)(n0 + b_row[i]) * ld + kz0 + kt + b_c8[i],
                       Bs + b_dst[i]);
        __syncthreads();

        bf16x8 af[MI], bfr[NI];
#pragma unroll
        for (int i = 0; i < MI; ++i)
            af[i] = *(const bf16x8*)(As + a_off[i]);
#pragma unroll
        for (int j = 0; j < NI; ++j)
            bfr[j] = *(const bf16x8*)(Bs + b_off[j]);
#pragma unroll
        for (int i = 0; i < MI; ++i)
#pragma unroll
            for (int j = 0; j < NI; ++j)
                acc[i][j] = __builtin_amdgcn_mfma_f32_16x16x32_bf16(
                    af[i], bfr[j], acc[i][j], 0, 0, 0);
    }

    // epilogue: C/D layout col=lane&15, row=(lane>>4)*4+reg (m89/m91)
    const int row_l = (lane >> 4) * 4;
#pragma unroll
    for (int j = 0; j < NI; ++j) {
        const int n = n0 + wn0 + j * 16 + r15;
        const float bv = (OMODE & 4) ? 0.f : bias[n];
#pragma unroll
        for (int i = 0; i < MI; ++i) {
            const int m = m0 + wm0 + i * 16 + row_l;
#pragma unroll
            for (int r = 0; r < 4; ++r) {
                float f = acc[i][j][r] + bv;
                if (ACT == 1) f = fmaxf(f, 0.f);
                if (ACT == 2) f = 1.f / (1.f + __expf(-f));
                const size_t idx = (size_t)(m + r) * N + n;
                if (OMODE & 1) Cb[idx] = (bf16_t)f;
                if (OMODE & 2) Cf[idx] = f;
                if (OMODE & 4) Cf[(size_t)blockIdx.z * ((size_t)M * N) + idx] = f;
            }
        }
    }
}

// sum 4 split-K partials + bias -> sigmoid -> out0 (f32) + cb (bf16)
__global__ __launch_bounds__(256)
void e3_reduce(const float* __restrict__ part, const float* __restrict__ be3,
               float* __restrict__ out0, bf16_t* __restrict__ cb) {
    const int t = blockIdx.x * 256 + threadIdx.x;     // 8192*64 threads
    const size_t P = (size_t)8192 * 64;
    float s = part[t] + part[t + P] + part[t + 2 * P] + part[t + 3 * P]
            + be3[t & 63];
    const float f = 1.f / (1.f + __expf(-s));
    out0[t] = f;
    cb[t] = (bf16_t)f;
}

extern "C" void kernel_launch(void* const* d_in, const int* in_sizes, int n_in,
                              void* d_out, int out_size, void* d_ws, size_t ws_size,
                              hipStream_t stream) {
    const float* x   = (const float*)d_in[0];
    const float* We1 = (const float*)d_in[1];
    const float* be1 = (const float*)d_in[2];
    const float* We2 = (const float*)d_in[3];
    const float* be2 = (const float*)d_in[4];
    const float* We3 = (const float*)d_in[5];
    const float* be3 = (const float*)d_in[6];
    const float* Wd1 = (const float*)d_in[7];
    const float* bd1 = (const float*)d_in[8];
    const float* Wd2 = (const float*)d_in[9];
    const float* bd2 = (const float*)d_in[10];
    const float* Wd3 = (const float*)d_in[11];
    const float* bd3 = (const float*)d_in[12];

    char* ws = (char*)d_ws;
    size_t off = 0;
    bf16_t* xb  = (bf16_t*)(ws + off); off += (size_t)8192 * 1024 * 2;
    bf16_t* w1t = (bf16_t*)(ws + off); off += (size_t)2048 * 1024 * 2;
    bf16_t* w2t = (bf16_t*)(ws + off); off += (size_t)2048 * 2048 * 2;
    bf16_t* w3t = (bf16_t*)(ws + off); off += (size_t)64   * 2048 * 2;
    bf16_t* w4t = (bf16_t*)(ws + off); off += (size_t)2048 * 64   * 2;
    bf16_t* w5t = (bf16_t*)(ws + off); off += (size_t)2048 * 2048 * 2;
    bf16_t* w6t = (bf16_t*)(ws + off); off += (size_t)1024 * 2048 * 2;
    bf16_t* ha  = (bf16_t*)(ws + off); off += (size_t)8192 * 2048 * 2;  // hidden ping
    bf16_t* hb  = (bf16_t*)(ws + off); off += (size_t)8192 * 2048 * 2;  // hidden pong
    bf16_t* cb  = (bf16_t*)(ws + off); off += (size_t)8192 * 64   * 2;
    float* e3part = (float*)ha;   // ha is dead between e2-consume and d1-write:
                                  // 4*8192*64*4B = 8MB << 32MB

    float* out0 = (float*)d_out;                    // control_vec [8192,64]
    float* out1 = out0 + (size_t)8192 * 64;         // state_vec   [8192,1024]

    // --- single merged conversion launch ---
    PrepArgs pa;
    pa.x = x; pa.xb = xb;
    pa.w[0] = We1; pa.w[1] = We2; pa.w[2] = We3;
    pa.w[3] = Wd1; pa.w[4] = Wd2; pa.w[5] = Wd3;
    pa.t[0] = w1t; pa.t[1] = w2t; pa.t[2] = w3t;
    pa.t[3] = w4t; pa.t[4] = w5t; pa.t[5] = w6t;
    prep<<<dim3(20736), dim3(32, 8), 0, stream>>>(pa);

    // --- 6-layer GEMM chain ---
    // e1: relu(x @ We1 + be1)   M=8192 K=1024 N=2048
    gemm_bt<128, 128, 64, 64, 1, 1><<<dim3(16, 64), 256, 0, stream>>>(
        xb, w1t, be1, ha, nullptr, 8192, 2048, 1024, 1024);
    // e2: relu(h @ We2 + be2)   K=2048 N=2048
    gemm_bt<128, 128, 64, 64, 1, 1><<<dim3(16, 64), 256, 0, stream>>>(
        ha, w2t, be2, hb, nullptr, 8192, 2048, 2048, 2048);
    // e3: split-K x4 partials (raw fp32), grid (1,64,4) = 256 blocks
    gemm_bt<128, 64, 32, 64, 0, 4><<<dim3(1, 64, 4), 256, 0, stream>>>(
        hb, w3t, nullptr, nullptr, e3part, 8192, 64, 512, 2048);
    e3_reduce<<<dim3(2048), 256, 0, stream>>>(e3part, be3, out0, cb);
    // d1: relu(c @ Wd1 + bd1)   K=64 N=2048
    gemm_bt<128, 128, 64, 64, 1, 1><<<dim3(16, 64), 256, 0, stream>>>(
        cb, w4t, bd1, ha, nullptr, 8192, 2048, 64, 64);
    // d2: relu(h @ Wd2 + bd2)   K=2048 N=2048
    gemm_bt<128, 128, 64, 64, 1, 1><<<dim3(16, 64), 256, 0, stream>>>(
        ha, w5t, bd2, hb, nullptr, 8192, 2048, 2048, 2048);
    // d3: h @ Wd3 + bd3 -> out1 (f32)   K=2048 N=1024
    gemm_bt<128, 128, 64, 64, 0, 2><<<dim3(8, 64), 256, 0, stream>>>(
        hb, w6t, bd3, nullptr, out1, 8192, 1024, 2048, 2048);
}

// Round 3
// 439.882 us; speedup vs baseline: 1.1951x; 1.1425x over previous
//
#include <hip/hip_runtime.h>
#include <hip/hip_bf16.h>
#include <cstdint>
#include <cstddef>

// ---------------------------------------------------------------------------
// AutoEncoder: x[8192,1024] -> enc(1024->2048->2048->64, relu/relu/sigmoid)
//             -> dec(64->2048->2048->1024, relu/relu/none)
// R3 changes vs R2:
//  - Double-buffered LDS: global_load_lds for tile k+1 issued before the
//    ds_read/MFMA of tile k -> one barrier per iter, memory latency overlapped
//    by compute instead of fully exposed (R2: ~1100 cyc/iter, MFMA only ~310).
//  - XCD-aware swizzle: 1D grid, lin%8 = XCD; each XCD owns an 8-Mrow x all-N
//    super-region -> A-panel working set 4MB = one XCD's L2.
//  - K-loop global addresses are precomputed per-chunk base pointers + kt.
// Kept from R2: LDS K-chunk swizzle (0 bank conflicts), merged prep, split-K e3.
// ---------------------------------------------------------------------------

typedef __bf16 bf16_t;
typedef bf16_t bf16x8 __attribute__((ext_vector_type(8)));
typedef bf16_t bf16x4 __attribute__((ext_vector_type(4)));
typedef float  floatx4 __attribute__((ext_vector_type(4)));

__device__ __forceinline__ void async_cp16(const bf16_t* gp, bf16_t* lp) {
    // global->LDS DMA, 16B/lane; LDS dest = wave-uniform base + lane*16
    __builtin_amdgcn_global_load_lds(
        (const __attribute__((address_space(1))) void*)gp,
        (__attribute__((address_space(3))) void*)lp, 16, 0, 0);
}

// ---------------------------------------------------------------------------
// Merged prep: x fp32->bf16 cast + 6 weight transpose+casts in one launch.
// ---------------------------------------------------------------------------
struct PrepArgs {
    const float* x; bf16_t* xb;
    const float* w[6]; bf16_t* t[6];
};

__device__ __forceinline__ void trans_tile(const float* __restrict__ in,
                                           bf16_t* __restrict__ out,
                                           int K, int N, int bx, int by,
                                           int tx, int ty,
                                           float (*tile)[33]) {
    const int n0 = bx * 32, k0 = by * 32;
#pragma unroll
    for (int i = 0; i < 32; i += 8)
        tile[ty + i][tx] = in[(size_t)(k0 + ty + i) * N + n0 + tx];
    __syncthreads();
#pragma unroll
    for (int i = 0; i < 32; i += 8)
        out[(size_t)(n0 + ty + i) * K + k0 + tx] = (bf16_t)tile[tx][ty + i];
}

__global__ __launch_bounds__(256) void prep(PrepArgs a) {
    __shared__ float tile[32][33];
    const int tx = threadIdx.x, ty = threadIdx.y;
    const int b = blockIdx.x;
    if (b < 8192) {                      // x cast: 8192*1024 elts, 4/thread
        const int i = (b * 256 + ty * 32 + tx) * 4;
        const float4 v = *(const float4*)(a.x + i);
        bf16x4 o;
        o[0] = (bf16_t)v.x; o[1] = (bf16_t)v.y;
        o[2] = (bf16_t)v.z; o[3] = (bf16_t)v.w;
        *(bf16x4*)(a.xb + i) = o;
        return;
    }
    int lb = b - 8192;
    if (lb < 2048)      { trans_tile(a.w[0], a.t[0], 1024, 2048, lb % 64, lb / 64, tx, ty, tile); return; }
    lb -= 2048;
    if (lb < 4096)      { trans_tile(a.w[1], a.t[1], 2048, 2048, lb % 64, lb / 64, tx, ty, tile); return; }
    lb -= 4096;
    if (lb < 128)       { trans_tile(a.w[2], a.t[2], 2048, 64,   lb % 2,  lb / 2,  tx, ty, tile); return; }
    lb -= 128;
    if (lb < 128)       { trans_tile(a.w[3], a.t[3], 64,   2048, lb % 64, lb / 64, tx, ty, tile); return; }
    lb -= 128;
    if (lb < 4096)      { trans_tile(a.w[4], a.t[4], 2048, 2048, lb % 64, lb / 64, tx, ty, tile); return; }
    lb -= 4096;
    trans_tile(a.w[5], a.t[5], 2048, 1024, lb % 32, lb / 32, tx, ty, tile);
}

// ---------------------------------------------------------------------------
// C[M,N] = act(A[M,K'] @ Bt[N,K']^T + bias), K-segment via blockIdx.y (split-K)
// Grid: dim3(GX*GY_blocks, Z). lin -> (bx,by) via XCD super-region swizzle.
// OMODE bit0: bf16 out, bit1: f32 out, bit2: f32 split-K partial (no bias/act)
// ACT: 0 none, 1 relu, 2 sigmoid
// LDS 16B-chunk swizzle: reader slot for K-group g at row r is (g+(r>>1))&3
// -> ds_read_b128 spread over all 8 bank-groups (0 conflicts, verified R2).
// ---------------------------------------------------------------------------
template<int BM, int BN, int WM, int WN, int ACT, int OMODE, int GX>
__global__ __launch_bounds__(256)
void gemm_bt(const bf16_t* __restrict__ A, const bf16_t* __restrict__ Bt,
             const float* __restrict__ bias,
             bf16_t* __restrict__ Cb, float* __restrict__ Cf,
             int M, int N, int K, int ld) {
    constexpr int BK = 32;
    constexpr int MI = WM / 16, NI = WN / 16;
    constexpr int WCOLS = BN / WN;
    static_assert((BM / WM) * (BN / WN) == 4, "4 waves");
    constexpr int A_CPW = (BM * BK) / (8 * 64 * 4);
    constexpr int B_CPW = (BN * BK) / (8 * 64 * 4);
    static_assert(A_CPW >= 1 && B_CPW >= 1, "tile too small");
    constexpr int ASZ = BM * BK, BSZ = BN * BK;

    __shared__ bf16_t As[2 * ASZ];
    __shared__ bf16_t Bs[2 * BSZ];

    // XCD swizzle: lin%8 = XCD (heuristic round-robin); each XCD gets an
    // 8-Mrow x GX-col super-region. Requires gridDim.x == GX*64.
    const int lin = blockIdx.x;
    const int xcd = lin & 7;
    const int loc = lin >> 3;
    const int by  = xcd * 8 + loc / GX;
    const int bx  = loc % GX;

    const int tid  = threadIdx.x;
    const int wave = tid >> 6;
    const int lane = tid & 63;
    const int m0 = by * BM;
    const int n0 = bx * BN;
    const int kz0 = blockIdx.y * K;
    const int wm0 = (wave / WCOLS) * WM;
    const int wn0 = (wave % WCOLS) * WN;
    const int r15 = lane & 15;
    const int kgc = lane >> 4;

    floatx4 acc[MI][NI];
#pragma unroll
    for (int i = 0; i < MI; ++i)
#pragma unroll
        for (int j = 0; j < NI; ++j)
            acc[i][j] = floatx4{0.f, 0.f, 0.f, 0.f};

    // staging: per-chunk global base pointers (advance by +kt) + LDS offsets
    const bf16_t* a_src[A_CPW];
    int a_dst[A_CPW];
#pragma unroll
    for (int i = 0; i < A_CPW; ++i) {
        const int cbase = (wave * A_CPW + i) * 64;
        const int chunk = cbase + lane;
        const int row = chunk >> 2;
        const int c8  = (((chunk & 3) - (row >> 1)) & 3) * 8;
        a_src[i] = A + (size_t)(m0 + row) * ld + kz0 + c8;
        a_dst[i] = cbase * 8;
    }
    const bf16_t* b_src[B_CPW];
    int b_dst[B_CPW];
#pragma unroll
    for (int i = 0; i < B_CPW; ++i) {
        const int cbase = (wave * B_CPW + i) * 64;
        const int chunk = cbase + lane;
        const int row = chunk >> 2;
        const int c8  = (((chunk & 3) - (row >> 1)) & 3) * 8;
        b_src[i] = Bt + (size_t)(n0 + row) * ld + kz0 + c8;
        b_dst[i] = cbase * 8;
    }
    int a_off[MI], b_off[NI];
#pragma unroll
    for (int i = 0; i < MI; ++i) {
        const int r = wm0 + i * 16 + r15;
        a_off[i] = r * BK + (((kgc + (r >> 1)) & 3) << 3);
    }
#pragma unroll
    for (int j = 0; j < NI; ++j) {
        const int r = wn0 + j * 16 + r15;
        b_off[j] = r * BK + (((kgc + (r >> 1)) & 3) << 3);
    }

    const int nIter = K / BK;
    // prologue: stage tile 0 into buffer 0
#pragma unroll
    for (int i = 0; i < A_CPW; ++i) async_cp16(a_src[i], As + a_dst[i]);
#pragma unroll
    for (int i = 0; i < B_CPW; ++i) async_cp16(b_src[i], Bs + b_dst[i]);

    for (int it = 0; it < nIter; ++it) {
        __syncthreads();  // drains DMA for buf[it&1]; protects buf[1-(it&1)]
        if (it + 1 < nIter) {
            const int kn = (it + 1) * BK;
            const int nb = (it + 1) & 1;
#pragma unroll
            for (int i = 0; i < A_CPW; ++i)
                async_cp16(a_src[i] + kn, As + nb * ASZ + a_dst[i]);
#pragma unroll
            for (int i = 0; i < B_CPW; ++i)
                async_cp16(b_src[i] + kn, Bs + nb * BSZ + b_dst[i]);
        }
        const bf16_t* curA = As + (it & 1) * ASZ;
        const bf16_t* curB = Bs + (it & 1) * BSZ;

        bf16x8 af[MI], bfr[NI];
#pragma unroll
        for (int i = 0; i < MI; ++i)
            af[i] = *(const bf16x8*)(curA + a_off[i]);
#pragma unroll
        for (int j = 0; j < NI; ++j)
            bfr[j] = *(const bf16x8*)(curB + b_off[j]);
#pragma unroll
        for (int i = 0; i < MI; ++i)
#pragma unroll
            for (int j = 0; j < NI; ++j)
                acc[i][j] = __builtin_amdgcn_mfma_f32_16x16x32_bf16(
                    af[i], bfr[j], acc[i][j], 0, 0, 0);
    }

    // epilogue: C/D layout col=lane&15, row=(lane>>4)*4+reg (m89/m91)
    const int row_l = (lane >> 4) * 4;
#pragma unroll
    for (int j = 0; j < NI; ++j) {
        const int n = n0 + wn0 + j * 16 + r15;
        const float bv = (OMODE & 4) ? 0.f : bias[n];
#pragma unroll
        for (int i = 0; i < MI; ++i) {
            const int m = m0 + wm0 + i * 16 + row_l;
#pragma unroll
            for (int r = 0; r < 4; ++r) {
                float f = acc[i][j][r] + bv;
                if (ACT == 1) f = fmaxf(f, 0.f);
                if (ACT == 2) f = 1.f / (1.f + __expf(-f));
                const size_t idx = (size_t)(m + r) * N + n;
                if (OMODE & 1) Cb[idx] = (bf16_t)f;
                if (OMODE & 2) Cf[idx] = f;
                if (OMODE & 4) Cf[(size_t)blockIdx.y * ((size_t)M * N) + idx] = f;
            }
        }
    }
}

// sum 4 split-K partials + bias -> sigmoid -> out0 (f32) + cb (bf16)
__global__ __launch_bounds__(256)
void e3_reduce(const float* __restrict__ part, const float* __restrict__ be3,
               float* __restrict__ out0, bf16_t* __restrict__ cb) {
    const int t = blockIdx.x * 256 + threadIdx.x;     // 8192*64 threads
    const size_t P = (size_t)8192 * 64;
    float s = part[t] + part[t + P] + part[t + 2 * P] + part[t + 3 * P]
            + be3[t & 63];
    const float f = 1.f / (1.f + __expf(-s));
    out0[t] = f;
    cb[t] = (bf16_t)f;
}

extern "C" void kernel_launch(void* const* d_in, const int* in_sizes, int n_in,
                              void* d_out, int out_size, void* d_ws, size_t ws_size,
                              hipStream_t stream) {
    const float* x   = (const float*)d_in[0];
    const float* We1 = (const float*)d_in[1];
    const float* be1 = (const float*)d_in[2];
    const float* We2 = (const float*)d_in[3];
    const float* be2 = (const float*)d_in[4];
    const float* We3 = (const float*)d_in[5];
    const float* be3 = (const float*)d_in[6];
    const float* Wd1 = (const float*)d_in[7];
    const float* bd1 = (const float*)d_in[8];
    const float* Wd2 = (const float*)d_in[9];
    const float* bd2 = (const float*)d_in[10];
    const float* Wd3 = (const float*)d_in[11];
    const float* bd3 = (const float*)d_in[12];

    char* ws = (char*)d_ws;
    size_t off = 0;
    bf16_t* xb  = (bf16_t*)(ws + off); off += (size_t)8192 * 1024 * 2;
    bf16_t* w1t = (bf16_t*)(ws + off); off += (size_t)2048 * 1024 * 2;
    bf16_t* w2t = (bf16_t*)(ws + off); off += (size_t)2048 * 2048 * 2;
    bf16_t* w3t = (bf16_t*)(ws + off); off += (size_t)64   * 2048 * 2;
    bf16_t* w4t = (bf16_t*)(ws + off); off += (size_t)2048 * 64   * 2;
    bf16_t* w5t = (bf16_t*)(ws + off); off += (size_t)2048 * 2048 * 2;
    bf16_t* w6t = (bf16_t*)(ws + off); off += (size_t)1024 * 2048 * 2;
    bf16_t* ha  = (bf16_t*)(ws + off); off += (size_t)8192 * 2048 * 2;  // hidden ping
    bf16_t* hb  = (bf16_t*)(ws + off); off += (size_t)8192 * 2048 * 2;  // hidden pong
    bf16_t* cb  = (bf16_t*)(ws + off); off += (size_t)8192 * 64   * 2;
    float* e3part = (float*)ha;   // ha dead between e2-consume and d1-write

    float* out0 = (float*)d_out;                    // control_vec [8192,64]
    float* out1 = out0 + (size_t)8192 * 64;         // state_vec   [8192,1024]

    PrepArgs pa;
    pa.x = x; pa.xb = xb;
    pa.w[0] = We1; pa.w[1] = We2; pa.w[2] = We3;
    pa.w[3] = Wd1; pa.w[4] = Wd2; pa.w[5] = Wd3;
    pa.t[0] = w1t; pa.t[1] = w2t; pa.t[2] = w3t;
    pa.t[3] = w4t; pa.t[4] = w5t; pa.t[5] = w6t;
    prep<<<dim3(20736), dim3(32, 8), 0, stream>>>(pa);

    // --- 6-layer GEMM chain (1D xy grid = GX*64 blocks, y = split-K) ---
    // e1: relu(x @ We1 + be1)   M=8192 K=1024 N=2048
    gemm_bt<128, 128, 64, 64, 1, 1, 16><<<dim3(16 * 64), 256, 0, stream>>>(
        xb, w1t, be1, ha, nullptr, 8192, 2048, 1024, 1024);
    // e2: relu(h @ We2 + be2)   K=2048 N=2048
    gemm_bt<128, 128, 64, 64, 1, 1, 16><<<dim3(16 * 64), 256, 0, stream>>>(
        ha, w2t, be2, hb, nullptr, 8192, 2048, 2048, 2048);
    // e3: split-K x4 partials (raw fp32), 256 blocks
    gemm_bt<128, 64, 32, 64, 0, 4, 1><<<dim3(64, 4), 256, 0, stream>>>(
        hb, w3t, nullptr, nullptr, e3part, 8192, 64, 512, 2048);
    e3_reduce<<<dim3(2048), 256, 0, stream>>>(e3part, be3, out0, cb);
    // d1: relu(c @ Wd1 + bd1)   K=64 N=2048
    gemm_bt<128, 128, 64, 64, 1, 1, 16><<<dim3(16 * 64), 256, 0, stream>>>(
        cb, w4t, bd1, ha, nullptr, 8192, 2048, 64, 64);
    // d2: relu(h @ Wd2 + bd2)   K=2048 N=2048
    gemm_bt<128, 128, 64, 64, 1, 1, 16><<<dim3(16 * 64), 256, 0, stream>>>(
        ha, w5t, bd2, hb, nullptr, 8192, 2048, 2048, 2048);
    // d3: h @ Wd3 + bd3 -> out1 (f32)   K=2048 N=1024
    gemm_bt<128, 128, 64, 64, 0, 2, 8><<<dim3(8 * 64), 256, 0, stream>>>(
        hb, w6t, bd3, nullptr, out1, 8192, 1024, 2048, 2048);
}